// Round 3
// baseline (5328.733 us; speedup 1.0000x reference)
//
#include <hip/hip_runtime.h>
#include <cstdint>
#include <cstddef>

#define BN 64
#define TN 512
#define DN 256
#define UN 256
#define NC 768            // 3*UN, order: r | z | h
#define SLOTS (TN + 5)    // slots TN..TN+3 = initial states, TN+4 = zero slot
#define ZSLOT (TN + 4)
#define JW 4              // CUs per batch (column-slices of 64)
#define NT 512            // threads per recurrent block (8 waves)

__device__ __forceinline__ float sigm(float x) {
  return 1.0f / (1.0f + __expf(-x));
}
__device__ __forceinline__ float tanh_fast(float x) {
  float e = __expf(-2.0f * x);
  return 2.0f / (1.0f + e) - 1.0f;
}

// ---------------- kernel 0: concat weights + biases + zero sync flags ----------------
__global__ __launch_bounds__(256) void build_wcat(
    const float* __restrict__ Wr, const float* __restrict__ Wz, const float* __restrict__ Wh,
    const float* __restrict__ br, const float* __restrict__ bz, const float* __restrict__ bh,
    float* __restrict__ wcat, float* __restrict__ bias,
    int* __restrict__ flagA, int* __restrict__ flagB)
{
  int idx = blockIdx.x * 256 + threadIdx.x;
  if (idx < DN * NC) {
    int k = idx / NC, c = idx % NC;
    float v;
    if (c < 256)      v = Wr[k * UN + c];
    else if (c < 512) v = Wz[k * UN + (c - 256)];
    else              v = Wh[k * UN + (c - 512)];
    wcat[idx] = v;
  }
  if (idx < NC) {
    bias[idx] = (idx < 256) ? br[idx] : ((idx < 512) ? bz[idx - 256] : bh[idx - 512]);
  }
  if (idx < BN * JW) { flagA[idx] = 0; flagB[idx] = 0; }   // replay-safe reset
}

// ---------------- kernel 1: P = X @ Wcat + bias  (fp32, LDS-tiled) ----------------
__global__ __launch_bounds__(256) void gemm_xw(
    const float* __restrict__ X, const float* __restrict__ Wc,
    const float* __restrict__ bias, float* __restrict__ P)
{
  __shared__ float As[32][68];
  __shared__ float Bs[32][64];
  const int tid = threadIdx.x;
  const int m0 = blockIdx.x * 64;
  const int n0 = blockIdx.y * 64;
  const int ty = tid >> 4, tx = tid & 15;
  float acc[4][4] = {};

  const int ar = tid >> 3;
  const int ak = (tid & 7) * 4;
  const int bk = tid >> 4;
  const int bn = (tid & 15) * 4;

  for (int k0 = 0; k0 < DN; k0 += 32) {
    float4 a0 = *(const float4*)(X + (size_t)(m0 + ar) * DN + k0 + ak);
    float4 a1 = *(const float4*)(X + (size_t)(m0 + 32 + ar) * DN + k0 + ak);
    As[ak + 0][ar] = a0.x; As[ak + 1][ar] = a0.y; As[ak + 2][ar] = a0.z; As[ak + 3][ar] = a0.w;
    As[ak + 0][32 + ar] = a1.x; As[ak + 1][32 + ar] = a1.y; As[ak + 2][32 + ar] = a1.z; As[ak + 3][32 + ar] = a1.w;
    *(float4*)&Bs[bk][bn]      = *(const float4*)(Wc + (size_t)(k0 + bk) * NC + n0 + bn);
    *(float4*)&Bs[bk + 16][bn] = *(const float4*)(Wc + (size_t)(k0 + bk + 16) * NC + n0 + bn);
    __syncthreads();
#pragma unroll
    for (int kk = 0; kk < 32; kk++) {
      float4 av = *(const float4*)&As[kk][ty * 4];
      float4 bv = *(const float4*)&Bs[kk][tx * 4];
      acc[0][0] += av.x * bv.x; acc[0][1] += av.x * bv.y; acc[0][2] += av.x * bv.z; acc[0][3] += av.x * bv.w;
      acc[1][0] += av.y * bv.x; acc[1][1] += av.y * bv.y; acc[1][2] += av.y * bv.z; acc[1][3] += av.y * bv.w;
      acc[2][0] += av.z * bv.x; acc[2][1] += av.z * bv.y; acc[2][2] += av.z * bv.z; acc[2][3] += av.z * bv.w;
      acc[3][0] += av.w * bv.x; acc[3][1] += av.w * bv.y; acc[3][2] += av.w * bv.z; acc[3][3] += av.w * bv.w;
    }
    __syncthreads();
  }
  float4 bb = *(const float4*)(bias + n0 + tx * 4);
#pragma unroll
  for (int i = 0; i < 4; i++) {
    float4 o;
    o.x = acc[i][0] + bb.x; o.y = acc[i][1] + bb.y;
    o.z = acc[i][2] + bb.z; o.w = acc[i][3] + bb.w;
    *(float4*)(P + (size_t)(m0 + ty * 4 + i) * NC + n0 + tx * 4) = o;
  }
}

// ---------------- kernel 2: the recurrence, JW=4 CUs per batch ----------------
// Block (b, j): owns output columns [64j, 64j+64). Weights FULLY resident:
//   Uh col-slice (256x64 = 64 KB) in VGPRs (wh[32] per thread),
//   Ur|Uz col-slices (2 x 64 KB) in LDS (wrz).
// Per active step, two cross-CU exchanges (same-XCD by block mapping b + 64j):
//   syncB: rs slices -> full rs for the Uh matvec; syncA: h slices -> full h for Ur/Uz proj.
__global__ __launch_bounds__(NT, 1) void recurrent_kernel(
    const float* __restrict__ P,
    const float* __restrict__ Ur, const float* __restrict__ Uz, const float* __restrict__ Uh,
    const int* __restrict__ dep, const int* __restrict__ mask,
    const float* __restrict__ init,
    float* __restrict__ out,
    float* __restrict__ buf_s, float* __restrict__ buf_pr, float* __restrict__ buf_pz,
    float* __restrict__ xrs, int* flagA, int* flagB)
{
  const int bj = blockIdx.x;
  const int b = bj & (BN - 1);
  const int j = bj >> 6;            // 0..3 column-slice id; blocks b,b+64,b+128,b+192 share an XCD
  const int col0 = j * 64;
  const int tid = threadIdx.x;
  const int c = tid & 63;

  // --- Uh column-slice in registers: wh[kk] = Uh[32*kg8 + kk][col0 + c] ---
  const int kg8 = tid >> 6;         // 0..7
  float wh[32];
  {
    const float* pu = Uh + (size_t)(32 * kg8) * UN + col0 + c;
#pragma unroll
    for (int kk = 0; kk < 32; kk++) wh[kk] = pu[(size_t)kk * UN];
  }

  __shared__ float4 wrz[2][256][16];        // 128 KB: Ur|Uz column-slices
  __shared__ float hfull[256];
  __shared__ float rfull[256];
  __shared__ float ls[4][64], lpr[4][64], lpz[4][64];
  __shared__ float lx[3][64];
  __shared__ float rsl[64], hsl[64], zvl[64];
  __shared__ float redB[8][64];
  __shared__ float redd[2][16][64];
  __shared__ float scur[64], prcur[64], pzcur[64];
  __shared__ int eff[TN];
  __shared__ int mloc[TN];
  __shared__ int deploc[TN * 3];

  // stage Ur|Uz slices into LDS (one-time, 128 KB)
  for (int i = tid; i < 2 * 256 * 16; i += NT) {
    int mat = i >> 12, k = (i >> 4) & 255, ch = i & 15;
    const float* src = mat ? Uz : Ur;
    wrz[mat][k][ch] = *(const float4*)(src + (size_t)k * UN + col0 + ch * 4);
  }
  for (int i = tid; i < TN; i += NT) mloc[i] = mask[b * TN + i];
  for (int i = tid; i < TN * 3; i += NT) deploc[i] = dep[i];
  if (tid < 64) { scur[c] = 0.0f; prcur[c] = 0.0f; pzcur[c] = 0.0f; }
  __syncthreads();

  // eff[] pure function of mask; computed once
  if (tid == 0) {
    int e = ZSLOT;
    for (int t2 = 0; t2 < TN; t2++) { if (mloc[t2]) e = t2; eff[t2] = e; }
  }

  const size_t bufS = (size_t)b * SLOTS * UN;               // full-vector layout
  const size_t bufP = (size_t)(b * JW + j) * SLOTS * 64;    // sliced layout

  // prologue: initial-state projections (local; full init vector read directly)
#pragma unroll 1
  for (int gg = 0; gg < 4; gg++) {
    if (tid < 256) hfull[tid] = init[((size_t)gg * BN + b) * UN + tid];
    __syncthreads();
    {
      int mat = tid >> 8, kg16 = (tid >> 4) & 15, ch = tid & 15;
      float4 a = {0, 0, 0, 0};
#pragma unroll
      for (int kk = 0; kk < 16; kk++) {
        int k = kg16 * 16 + kk;
        float hk = hfull[k];
        float4 w = wrz[mat][k][ch];
        a.x = fmaf(hk, w.x, a.x); a.y = fmaf(hk, w.y, a.y);
        a.z = fmaf(hk, w.z, a.z); a.w = fmaf(hk, w.w, a.w);
      }
      *(float4*)&redd[mat][kg16][ch * 4] = a;
    }
    __syncthreads();
    if (tid < 128) {
      int mat = tid >> 6;
      float s = 0.0f;
#pragma unroll
      for (int q = 0; q < 16; q++) s += redd[mat][q][c];
      if (mat == 0) buf_pr[bufP + (size_t)(TN + gg) * 64 + c] = s;
      else          buf_pz[bufP + (size_t)(TN + gg) * 64 + c] = s;
    }
    if (tid < 64) buf_s[bufS + (size_t)(TN + gg) * UN + col0 + c] = hfull[col0 + c];
    __syncthreads();
  }
  if (tid < 64) {
    buf_s[bufS + (size_t)ZSLOT * UN + col0 + c] = 0.0f;
    buf_pr[bufP + (size_t)ZSLOT * 64 + c] = 0.0f;
    buf_pz[bufP + (size_t)ZSLOT * 64 + c] = 0.0f;
  }
  __syncthreads();

  const size_t outB = (size_t)b * TN * UN;
  const size_t pB = (size_t)b * TN * NC;
  const int fbase = b * JW;
  int na = 0;                         // active-step counter (identical across the 4 CUs)

#pragma unroll 1
  for (int t = 0; t < TN; t++) {
    if (mloc[t] == 0) {
      if (tid < 64) out[outB + (size_t)t * UN + col0 + c] = 0.0f;
      continue;
    }
    na++;
    // ---- A: gather own-slice states + cached projections + x-row ----
    for (int i = tid; i < 960; i += NT) {
      if (i < 256) {
        int g = i >> 6, cc = i & 63;
        int src = (t == 0) ? (TN + g) : ((g == 0) ? -1 : eff[deploc[(t - 1) * 3 + (g - 1)]]);
        ls[g][cc] = (src < 0) ? scur[cc] : buf_s[bufS + (size_t)src * UN + col0 + cc];
      } else if (i < 768) {
        int i2 = i - 256;
        int arr = i2 >> 8, g = (i2 >> 6) & 3, cc = i2 & 63;
        int src = (t == 0) ? (TN + g) : ((g == 0) ? -1 : eff[deploc[(t - 1) * 3 + (g - 1)]]);
        if (arr == 0) lpr[g][cc] = (src < 0) ? prcur[cc] : buf_pr[bufP + (size_t)src * 64 + cc];
        else          lpz[g][cc] = (src < 0) ? pzcur[cc] : buf_pz[bufP + (size_t)src * 64 + cc];
      } else {
        int i2 = i - 768;
        int sel = i2 >> 6, cc = i2 & 63;
        lx[sel][cc] = P[pB + (size_t)t * NC + sel * UN + col0 + cc];
      }
    }
    __syncthreads();
    // ---- gates (own 64 cols) + publish rs slice ----
    if (tid < 64) {
      float s0 = ls[0][c], s1 = ls[1][c], s2 = ls[2][c], s3 = ls[3][c];
      float xr = lx[0][c];
      float rsv = sigm(xr + lpr[0][c]) * s0 + sigm(xr + lpr[1][c]) * s1
                + sigm(xr + lpr[2][c]) * s2 + sigm(xr + lpr[3][c]) * s3;
      rsl[c] = rsv;
      hsl[c] = (s0 + s1) + (s2 + s3);
      zvl[c] = sigm(lx[1][c] + ((lpz[0][c] + lpz[1][c]) + (lpz[2][c] + lpz[3][c])));
      xrs[(size_t)(fbase + j) * 64 + c] = rsv;
      __threadfence();                 // per-writer release (agent scope)
    }
    __syncthreads();
    if (tid == 0)
      __hip_atomic_store(&flagB[fbase + j], na, __ATOMIC_RELEASE, __HIP_MEMORY_SCOPE_AGENT);
    if (tid < JW - 1) {
      int jj = tid + (tid >= j ? 1 : 0);
      while (__hip_atomic_load(&flagB[fbase + jj], __ATOMIC_ACQUIRE, __HIP_MEMORY_SCOPE_AGENT) < na)
        __builtin_amdgcn_s_sleep(1);
    }
    __syncthreads();
    if (tid < 256) {
      int jj = tid >> 6;
      rfull[tid] = (jj == j) ? rsl[c]
        : __hip_atomic_load(&xrs[(size_t)(fbase + jj) * 64 + (tid & 63)],
                            __ATOMIC_RELAXED, __HIP_MEMORY_SCOPE_AGENT);
    }
    __syncthreads();
    // ---- B: full-rs @ Uh-slice (register-resident) ----
    {
      float a = 0.0f;
#pragma unroll
      for (int kk = 0; kk < 32; kk++) a = fmaf(rfull[32 * kg8 + kk], wh[kk], a);
      redB[kg8][c] = a;
    }
    __syncthreads();
    // ---- C: h (own cols), publish h slice ----
    if (tid < 64) {
      float hb = 0.0f;
#pragma unroll
      for (int q = 0; q < 8; q++) hb += redB[q][c];
      float ht = tanh_fast(lx[2][c] + hb);
      float z = zvl[c];
      float h = z * hsl[c] * 0.25f + (1.0f - z) * ht;
      scur[c] = h;
      out[outB + (size_t)t * UN + col0 + c] = h;
      buf_s[bufS + (size_t)t * UN + col0 + c] = h;
      __threadfence();
    }
    __syncthreads();
    if (tid == 0)
      __hip_atomic_store(&flagA[fbase + j], na, __ATOMIC_RELEASE, __HIP_MEMORY_SCOPE_AGENT);
    if (tid < JW - 1) {
      int jj = tid + (tid >= j ? 1 : 0);
      while (__hip_atomic_load(&flagA[fbase + jj], __ATOMIC_ACQUIRE, __HIP_MEMORY_SCOPE_AGENT) < na)
        __builtin_amdgcn_s_sleep(1);
    }
    __syncthreads();
    if (tid < 256) {
      int jj = tid >> 6;
      hfull[tid] = (jj == j) ? scur[c]
        : __hip_atomic_load(&buf_s[bufS + (size_t)t * UN + tid],
                            __ATOMIC_RELAXED, __HIP_MEMORY_SCOPE_AGENT);
    }
    __syncthreads();
    // ---- D: full-h @ Ur|Uz slices (LDS-resident) ----
    {
      int mat = tid >> 8, kg16 = (tid >> 4) & 15, ch = tid & 15;
      float4 a = {0, 0, 0, 0};
#pragma unroll
      for (int kk = 0; kk < 16; kk++) {
        int k = kg16 * 16 + kk;
        float hk = hfull[k];
        float4 w = wrz[mat][k][ch];
        a.x = fmaf(hk, w.x, a.x); a.y = fmaf(hk, w.y, a.y);
        a.z = fmaf(hk, w.z, a.z); a.w = fmaf(hk, w.w, a.w);
      }
      *(float4*)&redd[mat][kg16][ch * 4] = a;
    }
    __syncthreads();
    // ---- E: commit cached projections (own slices) ----
    if (tid < 128) {
      int mat = tid >> 6;
      float s = 0.0f;
#pragma unroll
      for (int q = 0; q < 16; q++) s += redd[mat][q][c];
      if (mat == 0) { prcur[c] = s; buf_pr[bufP + (size_t)t * 64 + c] = s; }
      else          { pzcur[c] = s; buf_pz[bufP + (size_t)t * 64 + c] = s; }
    }
    __syncthreads();
  }

  // epilogue: last_out, last_state (own slices)
  if (tid < 64) {
    float lst = scur[c];
    out[(size_t)BN * TN * UN + (size_t)b * UN + col0 + c] = mloc[TN - 1] ? lst : 0.0f;
    out[(size_t)BN * TN * UN + (size_t)BN * UN + (size_t)b * UN + col0 + c] = lst;
  }
}

extern "C" void kernel_launch(void* const* d_in, const int* in_sizes, int n_in,
                              void* d_out, int out_size, void* d_ws, size_t ws_size,
                              hipStream_t stream) {
  const float* inputs       = (const float*)d_in[0];
  const int*   dependencies = (const int*)d_in[1];
  const int*   mask         = (const int*)d_in[2];
  const float* initial      = (const float*)d_in[3];
  const float* Wz = (const float*)d_in[4];
  const float* Wr = (const float*)d_in[5];
  const float* Wh = (const float*)d_in[6];
  const float* Uz = (const float*)d_in[7];
  const float* Ur = (const float*)d_in[8];
  const float* Uh = (const float*)d_in[9];
  const float* bz = (const float*)d_in[10];
  const float* br = (const float*)d_in[11];
  const float* bh = (const float*)d_in[12];

  float* out = (float*)d_out;
  float* ws  = (float*)d_ws;
  float* wcat    = ws;                                    // 256*768
  float* bias    = wcat + (size_t)DN * NC;                // 768
  float* precomp = bias + NC;                             // B*T*768
  float* buf_s   = precomp + (size_t)BN * TN * NC;        // B*SLOTS*256 (full vectors)
  float* buf_pr  = buf_s + (size_t)BN * SLOTS * UN;       // B*JW*SLOTS*64 (sliced)
  float* buf_pz  = buf_pr + (size_t)BN * JW * SLOTS * 64;
  float* xrs     = buf_pz + (size_t)BN * JW * SLOTS * 64; // B*JW*64
  int*   flagA   = (int*)(xrs + (size_t)BN * JW * 64);    // B*JW
  int*   flagB   = flagA + BN * JW;                       // B*JW

  build_wcat<<<(DN * NC + 255) / 256, 256, 0, stream>>>(Wr, Wz, Wh, br, bz, bh, wcat, bias,
                                                        flagA, flagB);
  gemm_xw<<<dim3(BN * TN / 64, NC / 64), 256, 0, stream>>>(inputs, wcat, bias, precomp);
  recurrent_kernel<<<BN * JW, NT, 0, stream>>>(precomp, Ur, Uz, Uh, dependencies, mask, initial,
                                               out, buf_s, buf_pr, buf_pz, xrs, flagA, flagB);
}

// Round 4
// 2210.368 us; speedup vs baseline: 2.4108x; 2.4108x over previous
//
#include <hip/hip_runtime.h>
#include <cstdint>
#include <cstddef>

#define BN 64
#define TN 512
#define DN 256
#define UN 256
#define NC 768            // 3*UN, order: r | z | h
#define SLOTS (TN + 5)    // slots TN..TN+3 = initial states, TN+4 = zero slot
#define ZSLOT (TN + 4)

#define WROWS_LDS 6       // per 32-row wave-slice: rows 0..5 in LDS
#define WROWS_REG 2       // rows 6..7 in registers
#define WROWS_STR 24      // rows 8..31 streamed from L2

__device__ __forceinline__ float sigm(float x) {
  return 1.0f / (1.0f + __expf(-x));
}
__device__ __forceinline__ float tanh_fast(float x) {
  float e = __expf(-2.0f * x);
  return 2.0f / (1.0f + e) - 1.0f;
}

// ---------------- kernel 0: concat weights + biases ----------------
__global__ __launch_bounds__(256) void build_wcat(
    const float* __restrict__ Wr, const float* __restrict__ Wz, const float* __restrict__ Wh,
    const float* __restrict__ br, const float* __restrict__ bz, const float* __restrict__ bh,
    float* __restrict__ wcat, float* __restrict__ bias)
{
  int idx = blockIdx.x * 256 + threadIdx.x;
  if (idx < DN * NC) {
    int k = idx / NC, c = idx % NC;
    float v;
    if (c < 256)      v = Wr[k * UN + c];
    else if (c < 512) v = Wz[k * UN + (c - 256)];
    else              v = Wh[k * UN + (c - 512)];
    wcat[idx] = v;
  }
  if (idx < NC) {
    bias[idx] = (idx < 256) ? br[idx] : ((idx < 512) ? bz[idx - 256] : bh[idx - 512]);
  }
}

// ---------------- kernel 1: P = X @ Wcat + bias  (fp32, LDS-tiled) ----------------
__global__ __launch_bounds__(256) void gemm_xw(
    const float* __restrict__ X, const float* __restrict__ Wc,
    const float* __restrict__ bias, float* __restrict__ P)
{
  __shared__ float As[32][68];
  __shared__ float Bs[32][64];
  const int tid = threadIdx.x;
  const int m0 = blockIdx.x * 64;
  const int n0 = blockIdx.y * 64;
  const int ty = tid >> 4, tx = tid & 15;
  float acc[4][4] = {};

  const int ar = tid >> 3;
  const int ak = (tid & 7) * 4;
  const int bk = tid >> 4;
  const int bn = (tid & 15) * 4;

  for (int k0 = 0; k0 < DN; k0 += 32) {
    float4 a0 = *(const float4*)(X + (size_t)(m0 + ar) * DN + k0 + ak);
    float4 a1 = *(const float4*)(X + (size_t)(m0 + 32 + ar) * DN + k0 + ak);
    As[ak + 0][ar] = a0.x; As[ak + 1][ar] = a0.y; As[ak + 2][ar] = a0.z; As[ak + 3][ar] = a0.w;
    As[ak + 0][32 + ar] = a1.x; As[ak + 1][32 + ar] = a1.y; As[ak + 2][32 + ar] = a1.z; As[ak + 3][32 + ar] = a1.w;
    *(float4*)&Bs[bk][bn]      = *(const float4*)(Wc + (size_t)(k0 + bk) * NC + n0 + bn);
    *(float4*)&Bs[bk + 16][bn] = *(const float4*)(Wc + (size_t)(k0 + bk + 16) * NC + n0 + bn);
    __syncthreads();
#pragma unroll
    for (int kk = 0; kk < 32; kk++) {
      float4 av = *(const float4*)&As[kk][ty * 4];
      float4 bv = *(const float4*)&Bs[kk][tx * 4];
      acc[0][0] += av.x * bv.x; acc[0][1] += av.x * bv.y; acc[0][2] += av.x * bv.z; acc[0][3] += av.x * bv.w;
      acc[1][0] += av.y * bv.x; acc[1][1] += av.y * bv.y; acc[1][2] += av.y * bv.z; acc[1][3] += av.y * bv.w;
      acc[2][0] += av.z * bv.x; acc[2][1] += av.z * bv.y; acc[2][2] += av.z * bv.z; acc[2][3] += av.z * bv.w;
      acc[3][0] += av.w * bv.x; acc[3][1] += av.w * bv.y; acc[3][2] += av.w * bv.z; acc[3][3] += av.w * bv.w;
    }
    __syncthreads();
  }
  float4 bb = *(const float4*)(bias + n0 + tx * 4);
#pragma unroll
  for (int i = 0; i < 4; i++) {
    float4 o;
    o.x = acc[i][0] + bb.x; o.y = acc[i][1] + bb.y;
    o.z = acc[i][2] + bb.z; o.w = acc[i][3] + bb.w;
    *(float4*)(P + (size_t)(m0 + ty * 4 + i) * NC + n0 + tx * 4) = o;
  }
}

// ---------------- kernel 2: the recurrence, one block per batch ----------------
// 1024 threads = 16 waves. D-phase: wave wv -> (mat = wv&1: Ur|Uz, s = wv>>1: rows [32s,32s+32)),
// lane owns 4 output cols. Per slice: 6 rows LDS-resident, 2 reg-resident, 24 streamed (384 KB/step).
// Uh fully register-resident (wh[64] per thread, 4 k-groups of 256 threads).
// Next active step's gather/x loads issued during B-phase (latency hidden under B/C/D).
__global__ __launch_bounds__(1024, 1) void recurrent_kernel(
    const float* __restrict__ P,
    const float* __restrict__ Ur, const float* __restrict__ Uz, const float* __restrict__ Uh,
    const int* __restrict__ dep, const int* __restrict__ mask,
    const float* __restrict__ init,
    float* __restrict__ out,
    float* __restrict__ buf_s, float* __restrict__ buf_pr, float* __restrict__ buf_pz)
{
  const int b = blockIdx.x;
  const int tid = threadIdx.x;
  const int g4 = tid >> 8;        // 0..3 : B-phase k-group, A-phase state index
  const int u  = tid & 255;
  const int wv = tid >> 6;        // 0..15
  const int mat = wv & 1;         // 0 = Ur, 1 = Uz
  const int s   = wv >> 1;        // 0..7 : 32-row slice
  const int l   = tid & 63;

  // --- Uh register-resident: column u, k in [64*g4, 64*g4+64) ---
  float wh[64];
  {
    const float* pu = Uh + (size_t)(64 * g4) * UN + u;
#pragma unroll
    for (int kk = 0; kk < 64; kk++) wh[kk] = pu[(size_t)kk * UN];
  }
  // --- Ur/Uz reg-resident rows 32s+6, 32s+7, cols [4l,4l+4) ---
  const float* Um = mat ? Uz : Ur;
  float4 wrg0 = ((const float4*)Um)[(size_t)(32 * s + WROWS_LDS + 0) * 64 + l];
  float4 wrg1 = ((const float4*)Um)[(size_t)(32 * s + WROWS_LDS + 1) * 64 + l];

  __shared__ float4 wlds4[2][8][WROWS_LDS][64];      // 96 KB resident weight rows
  __shared__ float ls[4][256], lpr[4][256], lpz[4][256];
  __shared__ float lxf[NC];
  __shared__ float rs[256], hs[256], zv[256];
  __shared__ float red0[4][256];
  __shared__ float redd[2][8][256];
  __shared__ float scur[256], prcur[256], pzcur[256];
  __shared__ int eff[TN], nxt[TN], mloc[TN];
  __shared__ int deploc[TN * 3];

  // stage LDS-resident weight rows (rows 32s..32s+5 of each slice, both matrices)
  for (int i = tid; i < 2 * 8 * WROWS_LDS * 64; i += 1024) {
    int mm = i / (8 * WROWS_LDS * 64);
    int r2 = i % (8 * WROWS_LDS * 64);
    int ss = r2 / (WROWS_LDS * 64);
    int rr = (r2 / 64) % WROWS_LDS;
    int ll = i & 63;
    wlds4[mm][ss][rr][ll] = ((const float4*)(mm ? Uz : Ur))[(size_t)(32 * ss + rr) * 64 + ll];
  }
  for (int i = tid; i < TN; i += 1024) mloc[i] = mask[b * TN + i];
  for (int i = tid; i < TN * 3; i += 1024) deploc[i] = dep[i];

  const size_t bufBase = (size_t)b * SLOTS * UN;

  // prologue: stage initial states, zero slot, current-state LDS
  {
    float v = init[((size_t)g4 * BN + b) * UN + u];
    ls[g4][u] = v;
    buf_s[bufBase + (size_t)(TN + g4) * UN + u] = v;
    if (tid < 256) {
      scur[u] = 0.0f; prcur[u] = 0.0f; pzcur[u] = 0.0f;
      buf_s[bufBase + (size_t)ZSLOT * UN + u] = 0.0f;
      buf_pr[bufBase + (size_t)ZSLOT * UN + u] = 0.0f;
      buf_pz[bufBase + (size_t)ZSLOT * UN + u] = 0.0f;
    }
  }
  __syncthreads();

  // eff[] (last active <= t, else ZSLOT) and nxt[] (next active >= t, else TN): pure mask functions
  if (tid == 0) {
    int e = ZSLOT;
    for (int t2 = 0; t2 < TN; t2++) { if (mloc[t2]) e = t2; eff[t2] = e; }
  } else if (tid == 64) {
    int e = TN;
    for (int t2 = TN - 1; t2 >= 0; t2--) { if (mloc[t2]) e = t2; nxt[t2] = e; }
  }

  // ---- projection of a 256-vector through Ur|Uz: LDS rows + reg rows + streamed rows ----
  auto projD = [&](const float* hsrc) {
    const float* hb = hsrc + 32 * s;
    float4 a = {0, 0, 0, 0};
#pragma unroll
    for (int r = 0; r < WROWS_LDS; r++) {
      float hk = hb[r];
      float4 w = wlds4[mat][s][r][l];
      a.x = fmaf(hk, w.x, a.x); a.y = fmaf(hk, w.y, a.y);
      a.z = fmaf(hk, w.z, a.z); a.w = fmaf(hk, w.w, a.w);
    }
    {
      float hk = hb[WROWS_LDS + 0];
      a.x = fmaf(hk, wrg0.x, a.x); a.y = fmaf(hk, wrg0.y, a.y);
      a.z = fmaf(hk, wrg0.z, a.z); a.w = fmaf(hk, wrg0.w, a.w);
    }
    {
      float hk = hb[WROWS_LDS + 1];
      a.x = fmaf(hk, wrg1.x, a.x); a.y = fmaf(hk, wrg1.y, a.y);
      a.z = fmaf(hk, wrg1.z, a.z); a.w = fmaf(hk, wrg1.w, a.w);
    }
    const float4* p = (const float4*)Um + (size_t)(32 * s + WROWS_LDS + WROWS_REG) * 64 + l;
#pragma unroll 8
    for (int kk = 0; kk < WROWS_STR; kk++) {
      float hk = hb[WROWS_LDS + WROWS_REG + kk];
      float4 w = p[(size_t)kk * 64];
      a.x = fmaf(hk, w.x, a.x); a.y = fmaf(hk, w.y, a.y);
      a.z = fmaf(hk, w.z, a.z); a.w = fmaf(hk, w.w, a.w);
    }
    *(float4*)&redd[mat][s][4 * l] = a;
  };

  // initial-state projections through Ur|Uz (exact fp32)
#pragma unroll 1
  for (int gg = 0; gg < 4; gg++) {
    projD(&ls[gg][0]);
    __syncthreads();
    if (tid < 512) {
      int mm = tid >> 8, c = tid & 255;
      float v = 0.0f;
#pragma unroll
      for (int q = 0; q < 8; q++) v += redd[mm][q][c];
      (mm ? buf_pz : buf_pr)[bufBase + (size_t)(TN + gg) * UN + c] = v;
    }
    __syncthreads();
  }

  const size_t outB = (size_t)b * TN * UN;
  const size_t pB = (size_t)b * TN * NC;
  bool havePre = false;
  float eLs = 0.0f, eLpr = 0.0f, eLpz = 0.0f, eLx = 0.0f;
  int eSrc = -2;

#pragma unroll 1
  for (int t = 0; t < TN; t++) {
    if (mloc[t] == 0) {
      if (tid < 256) out[outB + (size_t)t * UN + u] = 0.0f;
      continue;                    // no barrier needed on masked steps
    }
    // ---- A: cold path only for the first active step (later steps pre-staged) ----
    if (!havePre) {
      if (t > 0 && g4 == 0) {
        ls[0][u] = scur[u]; lpr[0][u] = prcur[u]; lpz[0][u] = pzcur[u];
      } else {
        int src = (t == 0) ? (TN + g4) : eff[deploc[(t - 1) * 3 + (g4 - 1)]];
        size_t base = bufBase + (size_t)src * UN + u;
        ls[g4][u]  = buf_s[base];
        lpr[g4][u] = buf_pr[base];
        lpz[g4][u] = buf_pz[base];
      }
      if (tid < NC) lxf[tid] = P[pB + (size_t)t * NC + tid];
    }
    __syncthreads();                               // bar1: inputs staged
    // ---- gates (elementwise, tid<256) ----
    if (tid < 256) {
      float s0 = ls[0][u], s1 = ls[1][u], s2 = ls[2][u], s3 = ls[3][u];
      float xr = lxf[u];
      rs[u] = sigm(xr + lpr[0][u]) * s0 + sigm(xr + lpr[1][u]) * s1
            + sigm(xr + lpr[2][u]) * s2 + sigm(xr + lpr[3][u]) * s3;
      hs[u] = (s0 + s1) + (s2 + s3);
      zv[u] = sigm(lxf[256 + u] + ((lpz[0][u] + lpz[1][u]) + (lpz[2][u] + lpz[3][u])));
    }
    __syncthreads();                               // bar2: rs ready
    // ---- early-issue next active step's loads (latency hides under B/C/D) ----
    const int tn = (t + 1 < TN) ? nxt[t + 1] : TN;
    if (tn < TN) {
      if (g4 > 0) {
        eSrc = eff[deploc[(tn - 1) * 3 + (g4 - 1)]];
        if (eSrc != t) {                           // slot t not committed yet -> defer
          size_t base = bufBase + (size_t)eSrc * UN + u;
          eLs = buf_s[base]; eLpr = buf_pr[base]; eLpz = buf_pz[base];
        }
      }
      if (tid < NC) eLx = P[pB + (size_t)tn * NC + tid];
    }
    // ---- B: full-rs @ Uh (register-resident) ----
    {
      float a0 = 0, a1 = 0, a2 = 0, a3 = 0;
      const float4* v4 = (const float4*)&rs[64 * g4];
#pragma unroll
      for (int kk = 0; kk < 16; kk++) {
        float4 v = v4[kk];
        a0 += v.x * wh[4 * kk];     a1 += v.y * wh[4 * kk + 1];
        a2 += v.z * wh[4 * kk + 2]; a3 += v.w * wh[4 * kk + 3];
      }
      red0[g4][u] = (a0 + a1) + (a2 + a3);
    }
    __syncthreads();                               // bar3: red0 ready
    // ---- C: h, output, state commit ----
    if (tid < 256) {
      float ht = tanh_fast(lxf[512 + u] + ((red0[0][u] + red0[1][u]) + (red0[2][u] + red0[3][u])));
      float z = zv[u];
      float h = z * hs[u] * 0.25f + (1.0f - z) * ht;
      scur[u] = h;
      out[outB + (size_t)t * UN + u] = h;
      buf_s[bufBase + (size_t)t * UN + u] = h;
    }
    __syncthreads();                               // bar4: scur ready
    // ---- D: h @ Ur|Uz (96 KB LDS + 32 KB reg + 384 KB stream) ----
    projD(scur);
    __syncthreads();                               // bar5: redd ready
    // ---- E + A-consume (merged): commit projections, stage next step's inputs ----
    if (tid < 256) {
      float prn = 0.0f, pzn = 0.0f;
#pragma unroll
      for (int q = 0; q < 8; q++) { prn += redd[0][q][u]; pzn += redd[1][q][u]; }
      prcur[u] = prn; pzcur[u] = pzn;
      buf_pr[bufBase + (size_t)t * UN + u] = prn;
      buf_pz[bufBase + (size_t)t * UN + u] = pzn;
      if (tn < TN) { ls[0][u] = scur[u]; lpr[0][u] = prn; lpz[0][u] = pzn; }
    } else if (tn < TN) {
      if (eSrc == t) {                             // deferred: slot t == just-committed state
        float prn = 0.0f, pzn = 0.0f;
#pragma unroll
        for (int q = 0; q < 8; q++) { prn += redd[0][q][u]; pzn += redd[1][q][u]; }
        ls[g4][u] = scur[u]; lpr[g4][u] = prn; lpz[g4][u] = pzn;
      } else {
        ls[g4][u] = eLs; lpr[g4][u] = eLpr; lpz[g4][u] = eLpz;
      }
    }
    if (tn < TN && tid < NC) lxf[tid] = eLx;
    havePre = (tn < TN);
    // next active step's bar1 closes this region
  }

  // epilogue: last_out, last_state
  if (tid < 256) {
    float lst = scur[u];
    out[(size_t)BN * TN * UN + (size_t)b * UN + u] = mloc[TN - 1] ? lst : 0.0f;
    out[(size_t)BN * TN * UN + (size_t)BN * UN + (size_t)b * UN + u] = lst;
  }
}

extern "C" void kernel_launch(void* const* d_in, const int* in_sizes, int n_in,
                              void* d_out, int out_size, void* d_ws, size_t ws_size,
                              hipStream_t stream) {
  const float* inputs       = (const float*)d_in[0];
  const int*   dependencies = (const int*)d_in[1];
  const int*   mask         = (const int*)d_in[2];
  const float* initial      = (const float*)d_in[3];
  const float* Wz = (const float*)d_in[4];
  const float* Wr = (const float*)d_in[5];
  const float* Wh = (const float*)d_in[6];
  const float* Uz = (const float*)d_in[7];
  const float* Ur = (const float*)d_in[8];
  const float* Uh = (const float*)d_in[9];
  const float* bz = (const float*)d_in[10];
  const float* br = (const float*)d_in[11];
  const float* bh = (const float*)d_in[12];

  float* out = (float*)d_out;
  float* ws  = (float*)d_ws;
  float* wcat    = ws;                                   // 256*768
  float* bias    = wcat + (size_t)DN * NC;               // 768
  float* precomp = bias + NC;                            // B*T*768
  float* buf_s   = precomp + (size_t)BN * TN * NC;       // B*SLOTS*256 each
  float* buf_pr  = buf_s + (size_t)BN * SLOTS * UN;
  float* buf_pz  = buf_pr + (size_t)BN * SLOTS * UN;

  build_wcat<<<(DN * NC + 255) / 256, 256, 0, stream>>>(Wr, Wz, Wh, br, bz, bh, wcat, bias);
  gemm_xw<<<dim3(BN * TN / 64, NC / 64), 256, 0, stream>>>(inputs, wcat, bias, precomp);
  recurrent_kernel<<<BN, 1024, 0, stream>>>(precomp, Ur, Uz, Uh, dependencies, mask, initial,
                                            out, buf_s, buf_pr, buf_pz);
}